// Round 11
// baseline (86.000 us; speedup 1.0000x reference)
//
#include <hip/hip_runtime.h>
#include <math.h>

// VanillaSFNN: B=1024, T=1024, H=256, IN=2, OUT=2, DECAY=0.8
// Round 11 = R10 with the x-ring moved from SMEM (s_load) to VMEM:
// volatile loads disqualify SMRD selection -> global_load_dwordx4, whose
// completion IS fine-grained countable (vmcnt(3) before each consume, 3
// prefetches stay in flight). SMEM returns out-of-order -> consuming any
// ring entry forced lgkmcnt(0) drain incl. just-issued prefetches (~25cy/step
// exposed; matches R10's 65% busy). Uniform addr = 1 coalesced 16B req/wave.
// Packed math + med3 spike + op_sel broadcast unchanged -> bit-exact.

constexpr int T_STEPS = 1024;
constexpr int HIDDEN  = 256;
constexpr int BLK     = 128;
constexpr int NENT    = T_STEPS / 2;   // 512 f32x4 entries, 2 steps each

typedef float f32x2 __attribute__((ext_vector_type(2)));
typedef float f32x4 __attribute__((ext_vector_type(4)));

static __device__ __forceinline__ f32x2 pk_mul(f32x2 a, f32x2 b) {
    f32x2 d; asm("v_pk_mul_f32 %0, %1, %2" : "=v"(d) : "v"(a), "v"(b)); return d;
}
static __device__ __forceinline__ f32x2 pk_add(f32x2 a, f32x2 b) {
    f32x2 d; asm("v_pk_add_f32 %0, %1, %2" : "=v"(d) : "v"(a), "v"(b)); return d;
}
static __device__ __forceinline__ f32x2 pk_fma(f32x2 a, f32x2 b, f32x2 c) {
    f32x2 d; asm("v_pk_fma_f32 %0, %1, %2, %3" : "=v"(d) : "v"(a), "v"(b), "v"(c)); return d;
}
// lo = x.lo*w.lo, hi = x.lo*w.hi  (broadcast word0 of x)
static __device__ __forceinline__ f32x2 pk_mul_bc0(f32x2 x, f32x2 w) {
    f32x2 d; asm("v_pk_mul_f32 %0, %1, %2 op_sel:[0,0] op_sel_hi:[0,1]"
                 : "=v"(d) : "v"(x), "v"(w)); return d;
}
// lo = x.hi*w.lo, hi = x.hi*w.hi  (broadcast word1 of x)
static __device__ __forceinline__ f32x2 pk_mul_bc1(f32x2 x, f32x2 w) {
    f32x2 d; asm("v_pk_mul_f32 %0, %1, %2 op_sel:[1,0] op_sel_hi:[1,1]"
                 : "=v"(d) : "v"(x), "v"(w)); return d;
}
// spn = med3(-floor(v), -1, 0) in {-1,0};  -1 iff v >= 1
static __device__ __forceinline__ float spike_neg(float v) {
    return __builtin_amdgcn_fmed3f(-floorf(v), -1.0f, 0.0f);
}

__global__ __launch_bounds__(BLK) void sfnn_vmem_kernel(
    const float* __restrict__ x_seq,   // [B, T, 2]
    const float* __restrict__ W_in,    // [H, 2]
    const float* __restrict__ b_in,    // [H]
    const float* __restrict__ W_out,   // [2, H]
    const float* __restrict__ b_out,   // [2]
    const float* __restrict__ tau_m,   // [H]
    float* __restrict__ out)           // [B, 2]
{
    __shared__ float red[4];           // cross-wave epilogue partials only

    const int b   = blockIdx.x;
    const int tid = threadIdx.x;
    const int h0  = tid;
    const int h1  = tid + BLK;

    // x[b] ring source: volatile -> VMEM (global_load_dwordx4), counted vmcnt
    const volatile f32x4* __restrict__ xg =
        reinterpret_cast<const f32x4*>(x_seq) + (size_t)b * NENT;

    // --- per-lane packed constants ---
    f32x2 w0p, w1p, bip, alp, bep, c08;
    w0p.x = W_in[2 * h0];     w0p.y = W_in[2 * h1];
    w1p.x = W_in[2 * h0 + 1]; w1p.y = W_in[2 * h1 + 1];
    bip.x = b_in[h0];         bip.y = b_in[h1];
    alp.x = 1.0f / (1.0f + expf(-tau_m[h0]));
    alp.y = 1.0f / (1.0f + expf(-tau_m[h1]));
    bep.x = 1.0f - alp.x;     bep.y = 1.0f - alp.y;
    c08.x = 0.8f;             c08.y = 0.8f;

    f32x2 v  = {0.0f, 0.0f};
    f32x2 Sn = {0.0f, 0.0f};           // negated decayed spike sum

    // one LIF step for both h-units; XP = {x0(t), x1(t)} in a VGPR pair
    #define LIF_STEP(XP)                                                      \
        {                                                                     \
            f32x2 cur = pk_add(pk_add(pk_mul_bc0((XP), w0p),                  \
                                      pk_mul_bc1((XP), w1p)), bip);           \
            v = pk_add(pk_mul(v, alp), pk_mul(bep, cur));                     \
            f32x2 spn;                                                        \
            spn.x = spike_neg(v.x);                                           \
            spn.y = spike_neg(v.y);                                           \
            v  = pk_add(v, spn);                                              \
            Sn = pk_fma(c08, Sn, spn);                                        \
        }
    #define LIF2(Q)                                                           \
        LIF_STEP(__builtin_shufflevector((Q), (Q), 0, 1))                     \
        LIF_STEP(__builtin_shufflevector((Q), (Q), 2, 3))

    // --- main loop: 4-entry VGPR ring (prefetch distance 4 = 8 steps) ---
    f32x4 q0 = xg[0];
    f32x4 q1 = xg[1];
    f32x4 q2 = xg[2];
    f32x4 q3 = xg[3];
    for (int i = 0; i < NENT - 4; i += 4) {
        LIF2(q0) q0 = xg[i + 4];
        LIF2(q1) q1 = xg[i + 5];
        LIF2(q2) q2 = xg[i + 6];
        LIF2(q3) q3 = xg[i + 7];
    }
    LIF2(q0) LIF2(q1) LIF2(q2) LIF2(q3)
    #undef LIF2
    #undef LIF_STEP

    // --- epilogue: project -Sn onto W_out, wave shuffle-reduce, combine ---
    const float Sx = -Sn.x, Sy = -Sn.y;
    float r0 = fmaf(Sy, W_out[h1],          Sx * W_out[h0]);
    float r1 = fmaf(Sy, W_out[HIDDEN + h1], Sx * W_out[HIDDEN + h0]);
    #pragma unroll
    for (int off = 32; off > 0; off >>= 1) {
        r0 += __shfl_xor(r0, off, 64);
        r1 += __shfl_xor(r1, off, 64);
    }
    const int wave = tid >> 6;
    if ((tid & 63) == 0) {
        red[2 * wave]     = r0;
        red[2 * wave + 1] = r1;
    }
    __syncthreads();
    if (tid == 0) {
        const float geo = 5.0f;   // sum_{k=0}^{1023} 0.8^k rounds to 5.0f
        out[2 * b]     = (red[0] + red[2]) + b_out[0] * geo;
        out[2 * b + 1] = (red[1] + red[3]) + b_out[1] * geo;
    }
}

extern "C" void kernel_launch(void* const* d_in, const int* in_sizes, int n_in,
                              void* d_out, int out_size, void* d_ws, size_t ws_size,
                              hipStream_t stream) {
    const float* x_seq = (const float*)d_in[0];
    const float* W_in  = (const float*)d_in[1];
    const float* b_in  = (const float*)d_in[2];
    const float* W_out = (const float*)d_in[3];
    const float* b_out = (const float*)d_in[4];
    const float* tau_m = (const float*)d_in[5];
    float* out = (float*)d_out;

    sfnn_vmem_kernel<<<dim3(1024), dim3(BLK), 0, stream>>>(
        x_seq, W_in, b_in, W_out, b_out, tau_m, out);
}

// Round 12
// 63.108 us; speedup vs baseline: 1.3627x; 1.3627x over previous
//
#include <hip/hip_runtime.h>
#include <math.h>

// VanillaSFNN: B=1024, T=1024, H=256, IN=2, OUT=2, DECAY=0.8
// Round 12: R3's 1-wave/2-chain structure rehabilitated with all later fixes.
//   - block=64 (1 wave), grid=1024; lane runs TWO packed chains:
//     A=(tid,tid+64), B=(tid+128,tid+192) -> all latency hiding is in-wave ILP
//   - med3 spike (NO vcc): R3's failure was 8 vcc round-trips/2-step
//     serializing through the single vcc; med3 keeps both chains' spike
//     logic in pure parallel VALU dataflow
//   - plain 8KB LDS x, one ds_read_b128 per 2 steps shared by both chains,
//     op_sel broadcast; 4-entry ring (counted lgkmcnt, distance 8 steps)
// Arithmetic identical per half to the reference f32 op order -> bit-exact.

constexpr int T_STEPS = 1024;
constexpr int HIDDEN  = 256;
constexpr int BLK     = 64;
constexpr int NENT    = T_STEPS / 2;   // 512 f32x4 entries, 2 steps each

typedef float f32x2 __attribute__((ext_vector_type(2)));
typedef float f32x4 __attribute__((ext_vector_type(4)));

static __device__ __forceinline__ f32x2 pk_mul(f32x2 a, f32x2 b) {
    f32x2 d; asm("v_pk_mul_f32 %0, %1, %2" : "=v"(d) : "v"(a), "v"(b)); return d;
}
static __device__ __forceinline__ f32x2 pk_add(f32x2 a, f32x2 b) {
    f32x2 d; asm("v_pk_add_f32 %0, %1, %2" : "=v"(d) : "v"(a), "v"(b)); return d;
}
static __device__ __forceinline__ f32x2 pk_fma(f32x2 a, f32x2 b, f32x2 c) {
    f32x2 d; asm("v_pk_fma_f32 %0, %1, %2, %3" : "=v"(d) : "v"(a), "v"(b), "v"(c)); return d;
}
// lo = x.lo*w.lo, hi = x.lo*w.hi  (broadcast word0 of x)
static __device__ __forceinline__ f32x2 pk_mul_bc0(f32x2 x, f32x2 w) {
    f32x2 d; asm("v_pk_mul_f32 %0, %1, %2 op_sel:[0,0] op_sel_hi:[0,1]"
                 : "=v"(d) : "v"(x), "v"(w)); return d;
}
// lo = x.hi*w.lo, hi = x.hi*w.hi  (broadcast word1 of x)
static __device__ __forceinline__ f32x2 pk_mul_bc1(f32x2 x, f32x2 w) {
    f32x2 d; asm("v_pk_mul_f32 %0, %1, %2 op_sel:[1,0] op_sel_hi:[1,1]"
                 : "=v"(d) : "v"(x), "v"(w)); return d;
}
// spn = med3(-floor(v), -1, 0) in {-1,0};  -1 iff v >= 1  (no vcc!)
static __device__ __forceinline__ float spike_neg(float v) {
    return __builtin_amdgcn_fmed3f(-floorf(v), -1.0f, 0.0f);
}

__global__ __launch_bounds__(BLK) void sfnn_w1_kernel(
    const float* __restrict__ x_seq,   // [B, T, 2]
    const float* __restrict__ W_in,    // [H, 2]
    const float* __restrict__ b_in,    // [H]
    const float* __restrict__ W_out,   // [2, H]
    const float* __restrict__ b_out,   // [2]
    const float* __restrict__ tau_m,   // [H]
    float* __restrict__ out)           // [B, 2]
{
    __shared__ f32x4 xs[NENT];         // 8 KB: plain x[b]

    const int b   = blockIdx.x;
    const int tid = threadIdx.x;
    const int hA0 = tid,       hA1 = tid + 64;
    const int hB0 = tid + 128, hB1 = tid + 192;

    // --- stage x[b] into LDS (coalesced 16B, conflict-free) ---
    const f32x4* __restrict__ xg =
        reinterpret_cast<const f32x4*>(x_seq) + (size_t)b * NENT;
    #pragma unroll
    for (int k = 0; k < NENT / BLK; ++k)
        xs[tid + k * BLK] = xg[tid + k * BLK];

    // --- per-lane packed constants (two chains) ---
    f32x2 w0A, w1A, biA, alA, beA, w0B, w1B, biB, alB, beB, c08;
    w0A.x = W_in[2*hA0];   w0A.y = W_in[2*hA1];
    w1A.x = W_in[2*hA0+1]; w1A.y = W_in[2*hA1+1];
    biA.x = b_in[hA0];     biA.y = b_in[hA1];
    w0B.x = W_in[2*hB0];   w0B.y = W_in[2*hB1];
    w1B.x = W_in[2*hB0+1]; w1B.y = W_in[2*hB1+1];
    biB.x = b_in[hB0];     biB.y = b_in[hB1];
    alA.x = 1.0f / (1.0f + expf(-tau_m[hA0]));
    alA.y = 1.0f / (1.0f + expf(-tau_m[hA1]));
    alB.x = 1.0f / (1.0f + expf(-tau_m[hB0]));
    alB.y = 1.0f / (1.0f + expf(-tau_m[hB1]));
    beA.x = 1.0f - alA.x;  beA.y = 1.0f - alA.y;
    beB.x = 1.0f - alB.x;  beB.y = 1.0f - alB.y;
    c08.x = 0.8f;          c08.y = 0.8f;

    __syncthreads();

    f32x2 vA  = {0.0f, 0.0f}, vB  = {0.0f, 0.0f};
    f32x2 SnA = {0.0f, 0.0f}, SnB = {0.0f, 0.0f};

    // one LIF step for both chains; XP = {x0(t), x1(t)}
    #define LIF_STEP(XP)                                                      \
        {                                                                     \
            f32x2 curA = pk_add(pk_add(pk_mul_bc0((XP), w0A),                 \
                                       pk_mul_bc1((XP), w1A)), biA);          \
            f32x2 curB = pk_add(pk_add(pk_mul_bc0((XP), w0B),                 \
                                       pk_mul_bc1((XP), w1B)), biB);          \
            vA = pk_add(pk_mul(vA, alA), pk_mul(beA, curA));                  \
            vB = pk_add(pk_mul(vB, alB), pk_mul(beB, curB));                  \
            f32x2 spA, spB;                                                   \
            spA.x = spike_neg(vA.x);  spA.y = spike_neg(vA.y);                \
            spB.x = spike_neg(vB.x);  spB.y = spike_neg(vB.y);                \
            vA = pk_add(vA, spA);     vB = pk_add(vB, spB);                   \
            SnA = pk_fma(c08, SnA, spA);                                      \
            SnB = pk_fma(c08, SnB, spB);                                      \
        }
    #define LIF2(Q)                                                           \
        LIF_STEP(__builtin_shufflevector((Q), (Q), 0, 1))                     \
        LIF_STEP(__builtin_shufflevector((Q), (Q), 2, 3))

    // --- main loop: 4-entry register ring (prefetch distance 4 = 8 steps) ---
    f32x4 q0 = xs[0];
    f32x4 q1 = xs[1];
    f32x4 q2 = xs[2];
    f32x4 q3 = xs[3];
    for (int i = 0; i < NENT - 4; i += 4) {
        LIF2(q0) q0 = xs[i + 4];
        LIF2(q1) q1 = xs[i + 5];
        LIF2(q2) q2 = xs[i + 6];
        LIF2(q3) q3 = xs[i + 7];
    }
    LIF2(q0) LIF2(q1) LIF2(q2) LIF2(q3)
    #undef LIF2
    #undef LIF_STEP

    // --- epilogue: project 4 h-units onto W_out, single-wave shuffle reduce ---
    const float SAx = -SnA.x, SAy = -SnA.y, SBx = -SnB.x, SBy = -SnB.y;
    const float* __restrict__ Wo0 = W_out;
    const float* __restrict__ Wo1 = W_out + HIDDEN;
    float r0 = SAx * Wo0[hA0] + SAy * Wo0[hA1] + SBx * Wo0[hB0] + SBy * Wo0[hB1];
    float r1 = SAx * Wo1[hA0] + SAy * Wo1[hA1] + SBx * Wo1[hB0] + SBy * Wo1[hB1];
    #pragma unroll
    for (int off = 32; off > 0; off >>= 1) {
        r0 += __shfl_xor(r0, off, 64);
        r1 += __shfl_xor(r1, off, 64);
    }
    if (tid == 0) {
        const float geo = 5.0f;   // sum_{k=0}^{1023} 0.8^k rounds to 5.0f
        out[2 * b]     = r0 + b_out[0] * geo;
        out[2 * b + 1] = r1 + b_out[1] * geo;
    }
}

extern "C" void kernel_launch(void* const* d_in, const int* in_sizes, int n_in,
                              void* d_out, int out_size, void* d_ws, size_t ws_size,
                              hipStream_t stream) {
    const float* x_seq = (const float*)d_in[0];
    const float* W_in  = (const float*)d_in[1];
    const float* b_in  = (const float*)d_in[2];
    const float* W_out = (const float*)d_in[3];
    const float* b_out = (const float*)d_in[4];
    const float* tau_m = (const float*)d_in[5];
    float* out = (float*)d_out;

    sfnn_w1_kernel<<<dim3(1024), dim3(BLK), 0, stream>>>(
        x_seq, W_in, b_in, W_out, b_out, tau_m, out);
}

// Round 13
// 60.193 us; speedup vs baseline: 1.4287x; 1.0484x over previous
//
#include <hip/hip_runtime.h>
#include <math.h>

// VanillaSFNN: B=1024, T=1024, H=256, IN=2, OUT=2, DECAY=0.8
// Round 13: R10 (SGPR x-ring, 57.8us) with the SMEM drain stall removed.
// SMEM is out-of-order -> lgkmcnt(0) is a full drain; R10's interleaved
// consume/refill put a fresh s_load before every drain (~600cy exposed).
// Fix: ping-pong 2 groups x 8 entries (16 steps each), manual schedule:
//   [s_waitcnt lgkmcnt(0); sched_barrier]  // drains loads >=16 steps old
//   [refill other group: 2x s_load_dwordx16 (inline asm, untracked)]
//   [sched_barrier; consume current group: 16 LIF steps, no waits inside]
// Packed math + op_sel broadcast from SGPR pair + med3 spike unchanged
// -> bit-exact vs numpy reference.

constexpr int T_STEPS = 1024;
constexpr int HIDDEN  = 256;
constexpr int BLK     = 128;

typedef float f32x2  __attribute__((ext_vector_type(2)));
typedef float f32x16 __attribute__((ext_vector_type(16)));

static __device__ __forceinline__ f32x2 pk_mul(f32x2 a, f32x2 b) {
    f32x2 d; asm("v_pk_mul_f32 %0, %1, %2" : "=v"(d) : "v"(a), "v"(b)); return d;
}
static __device__ __forceinline__ f32x2 pk_add(f32x2 a, f32x2 b) {
    f32x2 d; asm("v_pk_add_f32 %0, %1, %2" : "=v"(d) : "v"(a), "v"(b)); return d;
}
static __device__ __forceinline__ f32x2 pk_fma(f32x2 a, f32x2 b, f32x2 c) {
    f32x2 d; asm("v_pk_fma_f32 %0, %1, %2, %3" : "=v"(d) : "v"(a), "v"(b), "v"(c)); return d;
}
// lo = x.lo*w.lo, hi = x.lo*w.hi  (x from SGPR pair, broadcast word0)
static __device__ __forceinline__ f32x2 pk_mul_bc0s(f32x2 x, f32x2 w) {
    f32x2 d; asm("v_pk_mul_f32 %0, %1, %2 op_sel:[0,0] op_sel_hi:[0,1]"
                 : "=v"(d) : "s"(x), "v"(w)); return d;
}
// lo = x.hi*w.lo, hi = x.hi*w.hi  (x from SGPR pair, broadcast word1)
static __device__ __forceinline__ f32x2 pk_mul_bc1s(f32x2 x, f32x2 w) {
    f32x2 d; asm("v_pk_mul_f32 %0, %1, %2 op_sel:[1,0] op_sel_hi:[1,1]"
                 : "=v"(d) : "s"(x), "v"(w)); return d;
}
// spn = med3(-floor(v), -1, 0) in {-1,0};  -1 iff v >= 1  (no vcc)
static __device__ __forceinline__ float spike_neg(float v) {
    return __builtin_amdgcn_fmed3f(-floorf(v), -1.0f, 0.0f);
}

__global__ __launch_bounds__(BLK) void sfnn_pp_kernel(
    const float* __restrict__ x_seq,   // [B, T, 2]
    const float* __restrict__ W_in,    // [H, 2]
    const float* __restrict__ b_in,    // [H]
    const float* __restrict__ W_out,   // [2, H]
    const float* __restrict__ b_out,   // [2]
    const float* __restrict__ tau_m,   // [H]
    float* __restrict__ out)           // [B, 2]
{
    __shared__ float red[4];

    const int b   = blockIdx.x;
    const int tid = threadIdx.x;
    const int h0  = tid;
    const int h1  = tid + BLK;

    // wave-uniform byte base of x[b] (8 KB span, fits imm+soffset addressing)
    const unsigned long long xbase =
        (unsigned long long)(x_seq + (size_t)b * T_STEPS * 2);

    // --- per-lane packed constants (VGPR; vmcnt path, independent of lgkm) ---
    f32x2 w0p, w1p, bip, alp, bep, c08;
    w0p.x = W_in[2 * h0];     w0p.y = W_in[2 * h1];
    w1p.x = W_in[2 * h0 + 1]; w1p.y = W_in[2 * h1 + 1];
    bip.x = b_in[h0];         bip.y = b_in[h1];
    alp.x = 1.0f / (1.0f + expf(-tau_m[h0]));
    alp.y = 1.0f / (1.0f + expf(-tau_m[h1]));
    bep.x = 1.0f - alp.x;     bep.y = 1.0f - alp.y;
    c08.x = 0.8f;             c08.y = 0.8f;

    f32x2 v  = {0.0f, 0.0f};
    f32x2 Sn = {0.0f, 0.0f};

    // manual wait + scheduling fence (rule #18: SB stops hoisting past wait)
    #define S_WAIT  asm volatile("s_waitcnt lgkmcnt(0)" ::: "memory");        \
                    __builtin_amdgcn_sched_barrier(0);
    #define SB      __builtin_amdgcn_sched_barrier(0);
    // untracked SMEM load: 16 dwords = 4 entries (8 steps)
    #define SLOAD16(D, SOFF, IMM)                                             \
        asm volatile("s_load_dwordx16 %0, %1, %2 offset:" #IMM                \
                     : "=s"(D) : "s"(xbase), "s"(SOFF));

    // one LIF step; XP = uniform {x0,x1} SGPR pair
    #define LIF_STEP(XP)                                                      \
        {                                                                     \
            f32x2 cur = pk_add(pk_add(pk_mul_bc0s((XP), w0p),                 \
                                      pk_mul_bc1s((XP), w1p)), bip);          \
            v = pk_add(pk_mul(v, alp), pk_mul(bep, cur));                     \
            f32x2 spn;                                                        \
            spn.x = spike_neg(v.x);                                           \
            spn.y = spike_neg(v.y);                                           \
            v  = pk_add(v, spn);                                              \
            Sn = pk_fma(c08, Sn, spn);                                        \
        }
    // consume one f32x16 = 8 steps
    #define LIF16(G)                                                          \
        LIF_STEP(__builtin_shufflevector((G), (G), 0, 1))                     \
        LIF_STEP(__builtin_shufflevector((G), (G), 2, 3))                     \
        LIF_STEP(__builtin_shufflevector((G), (G), 4, 5))                     \
        LIF_STEP(__builtin_shufflevector((G), (G), 6, 7))                     \
        LIF_STEP(__builtin_shufflevector((G), (G), 8, 9))                     \
        LIF_STEP(__builtin_shufflevector((G), (G), 10, 11))                   \
        LIF_STEP(__builtin_shufflevector((G), (G), 12, 13))                   \
        LIF_STEP(__builtin_shufflevector((G), (G), 14, 15))

    f32x16 A0, A1, B0, B1;             // two groups x 8 entries (16 steps)

    // --- prologue: A <- group 0 (entries 0..7 = bytes 0..127) ---
    {
        unsigned z = 0;
        SLOAD16(A0, z, 0)
        SLOAD16(A1, z, 64)
    }

    // 64 groups of 8 entries; pairs: refill G_{2p+1}, consume G_{2p};
    //                               refill G_{2p+2}, consume G_{2p+1}
    unsigned soff = 128;               // byte offset of G1
    for (int p = 0; p < 31; ++p) {
        S_WAIT                         // drains loads issued >=16 steps ago
        SLOAD16(B0, soff, 0)           // B <- next group
        SLOAD16(B1, soff, 64)
        SB
        LIF16(A0) LIF16(A1)            // 16 steps, no waits inside
        unsigned soff2 = soff + 128;
        S_WAIT
        SLOAD16(A0, soff2, 0)          // A <- group after next
        SLOAD16(A1, soff2, 64)
        SB
        LIF16(B0) LIF16(B1)
        soff += 256;
    }
    // tail: A holds G62; refill B <- G63 (bytes 8064..8191), consume both
    {
        S_WAIT
        SLOAD16(B0, soff, 0)
        SLOAD16(B1, soff, 64)
        SB
        LIF16(A0) LIF16(A1)            // G62
        S_WAIT
        SB
        LIF16(B0) LIF16(B1)            // G63
    }
    #undef LIF16
    #undef LIF_STEP
    #undef SLOAD16
    #undef S_WAIT
    #undef SB

    // --- epilogue: project -Sn onto W_out, wave shuffle-reduce, combine ---
    const float Sx = -Sn.x, Sy = -Sn.y;
    float r0 = fmaf(Sy, W_out[h1],          Sx * W_out[h0]);
    float r1 = fmaf(Sy, W_out[HIDDEN + h1], Sx * W_out[HIDDEN + h0]);
    #pragma unroll
    for (int off = 32; off > 0; off >>= 1) {
        r0 += __shfl_xor(r0, off, 64);
        r1 += __shfl_xor(r1, off, 64);
    }
    const int wave = tid >> 6;
    if ((tid & 63) == 0) {
        red[2 * wave]     = r0;
        red[2 * wave + 1] = r1;
    }
    __syncthreads();
    if (tid == 0) {
        const float geo = 5.0f;   // sum_{k=0}^{1023} 0.8^k rounds to 5.0f
        out[2 * b]     = (red[0] + red[2]) + b_out[0] * geo;
        out[2 * b + 1] = (red[1] + red[3]) + b_out[1] * geo;
    }
}

extern "C" void kernel_launch(void* const* d_in, const int* in_sizes, int n_in,
                              void* d_out, int out_size, void* d_ws, size_t ws_size,
                              hipStream_t stream) {
    const float* x_seq = (const float*)d_in[0];
    const float* W_in  = (const float*)d_in[1];
    const float* b_in  = (const float*)d_in[2];
    const float* W_out = (const float*)d_in[3];
    const float* b_out = (const float*)d_in[4];
    const float* tau_m = (const float*)d_in[5];
    float* out = (float*)d_out;

    sfnn_pp_kernel<<<dim3(1024), dim3(BLK), 0, stream>>>(
        x_seq, W_in, b_in, W_out, b_out, tau_m, out);
}

// Round 14
// 57.431 us; speedup vs baseline: 1.4975x; 1.0481x over previous
//
#include <hip/hip_runtime.h>
#include <math.h>

// VanillaSFNN: B=1024, T=1024, H=256, IN=2, OUT=2, DECAY=0.8
// Round 14 = R10 (best, 57.8us: SGPR x-ring via s_load, packed math, med3
// spike) with the ring window doubled to 8 entries (outer unroll x2) so the
// COMPILER's scheduler (which beat my manual R13 cadence) can batch 8 s_loads
// per group and halve lgkmcnt-drain frequency. Math untouched -> bit-exact.

constexpr int T_STEPS = 1024;
constexpr int HIDDEN  = 256;
constexpr int BLK     = 128;
constexpr int NENT    = T_STEPS / 2;   // 512 f32x4 entries, 2 steps each

typedef float f32x2 __attribute__((ext_vector_type(2)));
typedef float f32x4 __attribute__((ext_vector_type(4)));

static __device__ __forceinline__ f32x2 pk_mul(f32x2 a, f32x2 b) {
    f32x2 d; asm("v_pk_mul_f32 %0, %1, %2" : "=v"(d) : "v"(a), "v"(b)); return d;
}
static __device__ __forceinline__ f32x2 pk_add(f32x2 a, f32x2 b) {
    f32x2 d; asm("v_pk_add_f32 %0, %1, %2" : "=v"(d) : "v"(a), "v"(b)); return d;
}
static __device__ __forceinline__ f32x2 pk_fma(f32x2 a, f32x2 b, f32x2 c) {
    f32x2 d; asm("v_pk_fma_f32 %0, %1, %2, %3" : "=v"(d) : "v"(a), "v"(b), "v"(c)); return d;
}
// lo = x.lo*w.lo, hi = x.lo*w.hi  (x from SGPR pair, broadcast word0)
static __device__ __forceinline__ f32x2 pk_mul_bc0s(f32x2 x, f32x2 w) {
    f32x2 d; asm("v_pk_mul_f32 %0, %1, %2 op_sel:[0,0] op_sel_hi:[0,1]"
                 : "=v"(d) : "s"(x), "v"(w)); return d;
}
// lo = x.hi*w.lo, hi = x.hi*w.hi  (x from SGPR pair, broadcast word1)
static __device__ __forceinline__ f32x2 pk_mul_bc1s(f32x2 x, f32x2 w) {
    f32x2 d; asm("v_pk_mul_f32 %0, %1, %2 op_sel:[1,0] op_sel_hi:[1,1]"
                 : "=v"(d) : "s"(x), "v"(w)); return d;
}
// spn = med3(-floor(v), -1, 0) in {-1,0};  -1 iff v >= 1  (no vcc)
static __device__ __forceinline__ float spike_neg(float v) {
    return __builtin_amdgcn_fmed3f(-floorf(v), -1.0f, 0.0f);
}

__global__ __launch_bounds__(BLK) void sfnn_smem8_kernel(
    const float* __restrict__ x_seq,   // [B, T, 2]
    const float* __restrict__ W_in,    // [H, 2]
    const float* __restrict__ b_in,    // [H]
    const float* __restrict__ W_out,   // [2, H]
    const float* __restrict__ b_out,   // [2]
    const float* __restrict__ tau_m,   // [H]
    float* __restrict__ out)           // [B, 2]
{
    __shared__ float red[4];           // cross-wave epilogue partials only

    const int b   = blockIdx.x;
    const int tid = threadIdx.x;
    const int h0  = tid;
    const int h1  = tid + BLK;

    // wave-uniform base for x[b] -> compiler emits s_load for xg[i]
    const f32x4* __restrict__ xg =
        reinterpret_cast<const f32x4*>(x_seq) + (size_t)b * NENT;

    // --- per-lane packed constants ---
    f32x2 w0p, w1p, bip, alp, bep, c08;
    w0p.x = W_in[2 * h0];     w0p.y = W_in[2 * h1];
    w1p.x = W_in[2 * h0 + 1]; w1p.y = W_in[2 * h1 + 1];
    bip.x = b_in[h0];         bip.y = b_in[h1];
    alp.x = 1.0f / (1.0f + expf(-tau_m[h0]));
    alp.y = 1.0f / (1.0f + expf(-tau_m[h1]));
    bep.x = 1.0f - alp.x;     bep.y = 1.0f - alp.y;
    c08.x = 0.8f;             c08.y = 0.8f;

    f32x2 v  = {0.0f, 0.0f};
    f32x2 Sn = {0.0f, 0.0f};           // negated decayed spike sum

    // one LIF step for both h-units; XP = uniform {x0(t), x1(t)} in SGPRs
    #define LIF_STEP(XP)                                                      \
        {                                                                     \
            f32x2 cur = pk_add(pk_add(pk_mul_bc0s((XP), w0p),                 \
                                      pk_mul_bc1s((XP), w1p)), bip);          \
            v = pk_add(pk_mul(v, alp), pk_mul(bep, cur));                     \
            f32x2 spn;                                                        \
            spn.x = spike_neg(v.x);                                           \
            spn.y = spike_neg(v.y);                                           \
            v  = pk_add(v, spn);                                              \
            Sn = pk_fma(c08, Sn, spn);                                        \
        }
    #define LIF2(Q)                                                           \
        LIF_STEP(__builtin_shufflevector((Q), (Q), 0, 1))                     \
        LIF_STEP(__builtin_shufflevector((Q), (Q), 2, 3))

    // --- main loop: 8-entry SGPR ring (prefetch distance 8 = 16 steps),
    //     compiler-scheduled loads/waits (beat manual cadence in R13) ---
    f32x4 q0 = xg[0];
    f32x4 q1 = xg[1];
    f32x4 q2 = xg[2];
    f32x4 q3 = xg[3];
    f32x4 q4 = xg[4];
    f32x4 q5 = xg[5];
    f32x4 q6 = xg[6];
    f32x4 q7 = xg[7];
    for (int i = 0; i < NENT - 8; i += 8) {
        LIF2(q0) q0 = xg[i + 8];
        LIF2(q1) q1 = xg[i + 9];
        LIF2(q2) q2 = xg[i + 10];
        LIF2(q3) q3 = xg[i + 11];
        LIF2(q4) q4 = xg[i + 12];
        LIF2(q5) q5 = xg[i + 13];
        LIF2(q6) q6 = xg[i + 14];
        LIF2(q7) q7 = xg[i + 15];
    }
    LIF2(q0) LIF2(q1) LIF2(q2) LIF2(q3)
    LIF2(q4) LIF2(q5) LIF2(q6) LIF2(q7)
    #undef LIF2
    #undef LIF_STEP

    // --- epilogue: project -Sn onto W_out, wave shuffle-reduce, combine ---
    const float Sx = -Sn.x, Sy = -Sn.y;
    float r0 = fmaf(Sy, W_out[h1],          Sx * W_out[h0]);
    float r1 = fmaf(Sy, W_out[HIDDEN + h1], Sx * W_out[HIDDEN + h0]);
    #pragma unroll
    for (int off = 32; off > 0; off >>= 1) {
        r0 += __shfl_xor(r0, off, 64);
        r1 += __shfl_xor(r1, off, 64);
    }
    const int wave = tid >> 6;
    if ((tid & 63) == 0) {
        red[2 * wave]     = r0;
        red[2 * wave + 1] = r1;
    }
    __syncthreads();
    if (tid == 0) {
        const float geo = 5.0f;   // sum_{k=0}^{1023} 0.8^k rounds to 5.0f
        out[2 * b]     = (red[0] + red[2]) + b_out[0] * geo;
        out[2 * b + 1] = (red[1] + red[3]) + b_out[1] * geo;
    }
}

extern "C" void kernel_launch(void* const* d_in, const int* in_sizes, int n_in,
                              void* d_out, int out_size, void* d_ws, size_t ws_size,
                              hipStream_t stream) {
    const float* x_seq = (const float*)d_in[0];
    const float* W_in  = (const float*)d_in[1];
    const float* b_in  = (const float*)d_in[2];
    const float* W_out = (const float*)d_in[3];
    const float* b_out = (const float*)d_in[4];
    const float* tau_m = (const float*)d_in[5];
    float* out = (float*)d_out;

    sfnn_smem8_kernel<<<dim3(1024), dim3(BLK), 0, stream>>>(
        x_seq, W_in, b_in, W_out, b_out, tau_m, out);
}

// Round 15
// 50.541 us; speedup vs baseline: 1.7016x; 1.1363x over previous
//
#include <hip/hip_runtime.h>
#include <math.h>

// VanillaSFNN: B=1024, T=1024, H=256, IN=2, OUT=2, DECAY=0.8
// Round 15 = R14 (57.4us) with the spike computed in ONE op per component:
//   sp = clamp(floor(v))   (VOP3 clamp modifier: [0,1]; floor exact int)
//   sp = 1 iff v >= 1  -> bit-exact
// Reset:  v = pk_fma(sp, -1, v)   (exact product -> exact subtract)
// Accum:  S = pk_fma(0.8, S, sp)  (positive spike sum now)
// Step drops 13 -> 11 instructions; spike path off 2 ops.
// Structure unchanged: block=128 (2 waves/SIMD), SGPR 8-entry x-ring
// (s_load, compiler-scheduled), op_sel broadcast from SGPR pair.

constexpr int T_STEPS = 1024;
constexpr int HIDDEN  = 256;
constexpr int BLK     = 128;
constexpr int NENT    = T_STEPS / 2;   // 512 f32x4 entries, 2 steps each

typedef float f32x2 __attribute__((ext_vector_type(2)));
typedef float f32x4 __attribute__((ext_vector_type(4)));

static __device__ __forceinline__ f32x2 pk_mul(f32x2 a, f32x2 b) {
    f32x2 d; asm("v_pk_mul_f32 %0, %1, %2" : "=v"(d) : "v"(a), "v"(b)); return d;
}
static __device__ __forceinline__ f32x2 pk_add(f32x2 a, f32x2 b) {
    f32x2 d; asm("v_pk_add_f32 %0, %1, %2" : "=v"(d) : "v"(a), "v"(b)); return d;
}
static __device__ __forceinline__ f32x2 pk_fma(f32x2 a, f32x2 b, f32x2 c) {
    f32x2 d; asm("v_pk_fma_f32 %0, %1, %2, %3" : "=v"(d) : "v"(a), "v"(b), "v"(c)); return d;
}
// lo = x.lo*w.lo, hi = x.lo*w.hi  (x from SGPR pair, broadcast word0)
static __device__ __forceinline__ f32x2 pk_mul_bc0s(f32x2 x, f32x2 w) {
    f32x2 d; asm("v_pk_mul_f32 %0, %1, %2 op_sel:[0,0] op_sel_hi:[0,1]"
                 : "=v"(d) : "s"(x), "v"(w)); return d;
}
// lo = x.hi*w.lo, hi = x.hi*w.hi  (x from SGPR pair, broadcast word1)
static __device__ __forceinline__ f32x2 pk_mul_bc1s(f32x2 x, f32x2 w) {
    f32x2 d; asm("v_pk_mul_f32 %0, %1, %2 op_sel:[1,0] op_sel_hi:[1,1]"
                 : "=v"(d) : "s"(x), "v"(w)); return d;
}
// sp = clamp(floor(v)) in {0,1};  1 iff v >= 1   (single VALU op, no vcc)
static __device__ __forceinline__ float spike_pos(float v) {
    float d; asm("v_floor_f32_e64 %0, %1 clamp" : "=v"(d) : "v"(v)); return d;
}

__global__ __launch_bounds__(BLK) void sfnn_clamp_kernel(
    const float* __restrict__ x_seq,   // [B, T, 2]
    const float* __restrict__ W_in,    // [H, 2]
    const float* __restrict__ b_in,    // [H]
    const float* __restrict__ W_out,   // [2, H]
    const float* __restrict__ b_out,   // [2]
    const float* __restrict__ tau_m,   // [H]
    float* __restrict__ out)           // [B, 2]
{
    __shared__ float red[4];           // cross-wave epilogue partials only

    const int b   = blockIdx.x;
    const int tid = threadIdx.x;
    const int h0  = tid;
    const int h1  = tid + BLK;

    // wave-uniform base for x[b] -> compiler emits s_load for xg[i]
    const f32x4* __restrict__ xg =
        reinterpret_cast<const f32x4*>(x_seq) + (size_t)b * NENT;

    // --- per-lane packed constants ---
    f32x2 w0p, w1p, bip, alp, bep, c08, cm1;
    w0p.x = W_in[2 * h0];     w0p.y = W_in[2 * h1];
    w1p.x = W_in[2 * h0 + 1]; w1p.y = W_in[2 * h1 + 1];
    bip.x = b_in[h0];         bip.y = b_in[h1];
    alp.x = 1.0f / (1.0f + expf(-tau_m[h0]));
    alp.y = 1.0f / (1.0f + expf(-tau_m[h1]));
    bep.x = 1.0f - alp.x;     bep.y = 1.0f - alp.y;
    c08.x = 0.8f;             c08.y = 0.8f;
    cm1.x = -1.0f;            cm1.y = -1.0f;

    f32x2 v  = {0.0f, 0.0f};
    f32x2 Sp = {0.0f, 0.0f};           // decayed spike sum (positive)

    // one LIF step for both h-units; XP = uniform {x0(t), x1(t)} in SGPRs
    // 11 VALU: 4 cur + 3 v-update + 2 spike + 1 reset + 1 accum
    #define LIF_STEP(XP)                                                      \
        {                                                                     \
            f32x2 cur = pk_add(pk_add(pk_mul_bc0s((XP), w0p),                 \
                                      pk_mul_bc1s((XP), w1p)), bip);          \
            v = pk_add(pk_mul(v, alp), pk_mul(bep, cur));                     \
            f32x2 sp;                                                         \
            sp.x = spike_pos(v.x);                                            \
            sp.y = spike_pos(v.y);                                            \
            v  = pk_fma(sp, cm1, v);       /* v -= sp, exact */               \
            Sp = pk_fma(c08, Sp, sp);      /* S = 0.8*S + sp */               \
        }
    #define LIF2(Q)                                                           \
        LIF_STEP(__builtin_shufflevector((Q), (Q), 0, 1))                     \
        LIF_STEP(__builtin_shufflevector((Q), (Q), 2, 3))

    // --- main loop: 8-entry SGPR ring (prefetch distance 8 = 16 steps) ---
    f32x4 q0 = xg[0];
    f32x4 q1 = xg[1];
    f32x4 q2 = xg[2];
    f32x4 q3 = xg[3];
    f32x4 q4 = xg[4];
    f32x4 q5 = xg[5];
    f32x4 q6 = xg[6];
    f32x4 q7 = xg[7];
    for (int i = 0; i < NENT - 8; i += 8) {
        LIF2(q0) q0 = xg[i + 8];
        LIF2(q1) q1 = xg[i + 9];
        LIF2(q2) q2 = xg[i + 10];
        LIF2(q3) q3 = xg[i + 11];
        LIF2(q4) q4 = xg[i + 12];
        LIF2(q5) q5 = xg[i + 13];
        LIF2(q6) q6 = xg[i + 14];
        LIF2(q7) q7 = xg[i + 15];
    }
    LIF2(q0) LIF2(q1) LIF2(q2) LIF2(q3)
    LIF2(q4) LIF2(q5) LIF2(q6) LIF2(q7)
    #undef LIF2
    #undef LIF_STEP

    // --- epilogue: project Sp onto W_out, wave shuffle-reduce, combine ---
    const float Sx = Sp.x, Sy = Sp.y;
    float r0 = fmaf(Sy, W_out[h1],          Sx * W_out[h0]);
    float r1 = fmaf(Sy, W_out[HIDDEN + h1], Sx * W_out[HIDDEN + h0]);
    #pragma unroll
    for (int off = 32; off > 0; off >>= 1) {
        r0 += __shfl_xor(r0, off, 64);
        r1 += __shfl_xor(r1, off, 64);
    }
    const int wave = tid >> 6;
    if ((tid & 63) == 0) {
        red[2 * wave]     = r0;
        red[2 * wave + 1] = r1;
    }
    __syncthreads();
    if (tid == 0) {
        const float geo = 5.0f;   // sum_{k=0}^{1023} 0.8^k rounds to 5.0f
        out[2 * b]     = (red[0] + red[2]) + b_out[0] * geo;
        out[2 * b + 1] = (red[1] + red[3]) + b_out[1] * geo;
    }
}

extern "C" void kernel_launch(void* const* d_in, const int* in_sizes, int n_in,
                              void* d_out, int out_size, void* d_ws, size_t ws_size,
                              hipStream_t stream) {
    const float* x_seq = (const float*)d_in[0];
    const float* W_in  = (const float*)d_in[1];
    const float* b_in  = (const float*)d_in[2];
    const float* W_out = (const float*)d_in[3];
    const float* b_out = (const float*)d_in[4];
    const float* tau_m = (const float*)d_in[5];
    float* out = (float*)d_out;

    sfnn_clamp_kernel<<<dim3(1024), dim3(BLK), 0, stream>>>(
        x_seq, W_in, b_in, W_out, b_out, tau_m, out);
}